// Round 2
// baseline (1305.298 us; speedup 1.0000x reference)
//
#include <hip/hip_runtime.h>
#include <hip/hip_bf16.h>

typedef __hip_bfloat16 bf16;
typedef __attribute__((ext_vector_type(8))) short short8;
typedef __attribute__((ext_vector_type(4))) float floatx4;

struct bf16x4 { bf16 a, b, c, d; };  // 8-byte packed store unit

// ---- problem constants ----
// B=2, S=4096, T=8192 tokens
// out shape (2, 96, 4096, 192) fp32: b-stride 75497472, head-stride 786432
#define OUT_BSTRIDE 75497472u
#define OUT_HSTRIDE 786432u

__device__ __forceinline__ void gload_lds16(const bf16* g, bf16* l) {
    __builtin_amdgcn_global_load_lds((const __attribute__((address_space(1))) void*)g,
                                     (__attribute__((address_space(3))) void*)l,
                                     16, 0, 0);
}

// ---------------------------------------------------------------------------
// fp32 -> bf16 conversion, grid-stride, float4 in / 8B out. n % 4 == 0.
// ---------------------------------------------------------------------------
__global__ __launch_bounds__(256) void cvt_f32_bf16(const float* __restrict__ src,
                                                    bf16* __restrict__ dst, int n4) {
    const int stride = gridDim.x * blockDim.x;
    for (int i = blockIdx.x * blockDim.x + threadIdx.x; i < n4; i += stride) {
        const float4 v = ((const float4*)src)[i];
        bf16x4 o;
        o.a = __float2bfloat16(v.x);
        o.b = __float2bfloat16(v.y);
        o.c = __float2bfloat16(v.z);
        o.d = __float2bfloat16(v.w);
        ((bf16x4*)dst)[i] = o;
    }
}

// ---------------------------------------------------------------------------
// 256x256 tile, BK=64, 8-wave (2Mx4N), 8-phase counted-vmcnt bf16 GEMM.
// C = A * B^T.
// MODE 0: A=hid_b (K=4096). by<6 -> B=q_a_w (N=1536) -> Cq bf16
//         by>=6 -> B=kv_a_w (N=576, row-clamp + store-mask) -> Ckv bf16
// MODE 1: A=q_a_norm (K=1536), B=q_b_w -> Of fp32, q layout + pe permute
// MODE 2: A=ckv_norm (lda=576, K=512), B=kv_b_w -> Of fp32, k_nope/value
//
// Schedule (per K-tile c, 4 phases, raw s_barrier — NO vmcnt(0) in steady
// state):
//   p1: read a0(8xb128)+b0(4); stage B-half0(c+1) -> buf^1 ; MFMA q(0,0)
//   p2: read a1(8);            stage B-half1(c+1) -> buf^1 ; MFMA q(1,0)
//   p3: read b1(4);            stage A-half0(c+2) -> buf   ; MFMA q(0,1)
//   p4:                        stage A-half1(c+2) -> buf   ; MFMA q(1,1)
//        then s_waitcnt vmcnt(4) (leaves A(c+2) in flight) ; barrier
// LDS swizzle: 16B-slot index ^= (row&7); global source chunk pre-swizzled so
// the global_load_lds destination stays linear (both-sides-or-neither rule).
// XCD swizzle: bijective chunked remap (nwg % 8 == 0 for all grids).
// ---------------------------------------------------------------------------
template <int MODE>
__global__ __launch_bounds__(512) void gemm8(const bf16* __restrict__ A,
                                             const bf16* __restrict__ Bq,
                                             const bf16* __restrict__ Bkv,
                                             bf16* __restrict__ Cq,
                                             bf16* __restrict__ Ckv,
                                             float* __restrict__ Of) {
    constexpr int K   = (MODE == 0) ? 4096 : (MODE == 1) ? 1536 : 512;
    constexpr int LDA = (MODE == 0) ? 4096 : (MODE == 1) ? 1536 : 576;
    constexpr int LDB = (MODE == 0) ? 4096 : (MODE == 1) ? 1536 : 512;
    constexpr int NT  = K / 64;

    __shared__ __align__(16) bf16 sA[2][2][128 * 64];  // [buf][half][row*64+k]
    __shared__ __align__(16) bf16 sB[2][2][128 * 64];

    const int tid = threadIdx.x;

    // ---- XCD-aware block swizzle (gridDim.x == 32 in all modes) ----
    const int nwg = 32 * gridDim.y;
    const int lin = blockIdx.y * 32 + blockIdx.x;
    const int cpx = nwg >> 3;
    const int swb = (lin & 7) * cpx + (lin >> 3);
    const int bx  = swb & 31;
    const int by  = swb >> 5;

    const int m0 = bx * 256;

    const bf16* Bsel;
    bf16* Cb = nullptr;
    int n0, nmax = 0x40000000, ldc = 0;
    if constexpr (MODE == 0) {
        if (by < 6) { Bsel = Bq;  n0 = by * 256;       nmax = 1536; ldc = 1536; Cb = Cq; }
        else        { Bsel = Bkv; n0 = (by - 6) * 256; nmax = 576;  ldc = 576;  Cb = Ckv; }
    } else {
        Bsel = Bq; n0 = by * 256;
    }

    // ---- staging addressing: idx = tid + l*512 ; row = idx>>3 ; chunk = idx&7
    // pre-swizzle global source chunk: chunk ^ (row&7)  (same for l=0,1)
    const int srow   = tid >> 3;                  // 0..63
    const int schunk = (tid & 7) ^ (srow & 7);
    const bf16* gA[4];
    const bf16* gB[4];
#pragma unroll
    for (int g = 0; g < 4; ++g) {
        gA[g] = A + (size_t)(m0 + srow + g * 64) * LDA + schunk * 8;
        int rr = n0 + srow + g * 64;
        if constexpr (MODE == 0) { if (rr > nmax - 1) rr = nmax - 1; }
        gB[g] = Bsel + (size_t)rr * LDB + schunk * 8;
    }

    auto stageA = [&](int bb, int h, int k0) {
        bf16* d = &sA[bb][h][tid * 8];
        gload_lds16(gA[2 * h] + k0, d);
        gload_lds16(gA[2 * h + 1] + k0, d + 4096);
    };
    auto stageB = [&](int bb, int h, int k0) {
        bf16* d = &sB[bb][h][tid * 8];
        gload_lds16(gB[2 * h] + k0, d);
        gload_lds16(gB[2 * h + 1] + k0, d + 4096);
    };

    // ---- fragment read addressing (swizzled) ----
    const int lane = tid & 63;
    const int wid  = tid >> 6;        // 0..7
    const int wm   = wid >> 2;        // 0..1 -> rows wm*128..+127
    const int wn   = wid & 3;         // 0..3 -> cols wn*64..+63
    const int ln   = lane & 15;
    const int q4   = lane >> 4;       // 0..3
    const int swz  = ln & 7;          // row&7 for all this lane's frag rows
    const int aoff0 = ln * 64 + ((q4 ^ swz) * 8);        // kk=0
    const int aoff1 = ln * 64 + (((4 + q4) ^ swz) * 8);  // kk=1

    floatx4 acc[8][4];
#pragma unroll
    for (int i = 0; i < 8; ++i)
#pragma unroll
        for (int j = 0; j < 4; ++j) acc[i][j] = (floatx4){0.f, 0.f, 0.f, 0.f};

    // ---- prologue: K0 fully, K1 A-halves; vmcnt(4) leaves K1:A in flight ----
    stageA(0, 0, 0);  stageA(0, 1, 0);
    stageB(0, 0, 0);  stageB(0, 1, 0);
    stageA(1, 0, 64); stageA(1, 1, 64);
    asm volatile("s_waitcnt vmcnt(4)" ::: "memory");
    __builtin_amdgcn_s_barrier();
    asm volatile("" ::: "memory");

    short8 a0[4][2], a1[4][2], b0[2][2], b1[2][2];

    for (int c = 0; c < NT; ++c) {
        const int bb = c & 1;
        const bf16* hA = &sA[bb][wm][0];
        const bf16* hB = &sB[bb][wn >> 1][(wn & 1) * 4096];
        const int kn1 = (c + 1) * 64;
        const int kn2 = (c + 2) * 64;

        // ================= phase 1 =================
#pragma unroll
        for (int i = 0; i < 4; ++i) {
            a0[i][0] = *(const short8*)(hA + i * 1024 + aoff0);
            a0[i][1] = *(const short8*)(hA + i * 1024 + aoff1);
        }
#pragma unroll
        for (int j = 0; j < 2; ++j) {
            b0[j][0] = *(const short8*)(hB + j * 1024 + aoff0);
            b0[j][1] = *(const short8*)(hB + j * 1024 + aoff1);
        }
        if (c + 1 < NT) stageB(bb ^ 1, 0, kn1);
        __builtin_amdgcn_s_barrier();
        asm volatile("s_waitcnt lgkmcnt(0)" ::: "memory");
        __builtin_amdgcn_s_setprio(1);
#pragma unroll
        for (int i = 0; i < 4; ++i)
#pragma unroll
            for (int j = 0; j < 2; ++j) {
                acc[i][j] = __builtin_amdgcn_mfma_f32_16x16x32_bf16(a0[i][0], b0[j][0], acc[i][j], 0, 0, 0);
                acc[i][j] = __builtin_amdgcn_mfma_f32_16x16x32_bf16(a0[i][1], b0[j][1], acc[i][j], 0, 0, 0);
            }
        __builtin_amdgcn_s_setprio(0);
        __builtin_amdgcn_s_barrier();
        asm volatile("" ::: "memory");

        // ================= phase 2 =================
#pragma unroll
        for (int i = 0; i < 4; ++i) {
            a1[i][0] = *(const short8*)(hA + 4096 + i * 1024 + aoff0);
            a1[i][1] = *(const short8*)(hA + 4096 + i * 1024 + aoff1);
        }
        if (c + 1 < NT) stageB(bb ^ 1, 1, kn1);
        __builtin_amdgcn_s_barrier();
        asm volatile("s_waitcnt lgkmcnt(0)" ::: "memory");
        __builtin_amdgcn_s_setprio(1);
#pragma unroll
        for (int i = 0; i < 4; ++i)
#pragma unroll
            for (int j = 0; j < 2; ++j) {
                acc[4 + i][j] = __builtin_amdgcn_mfma_f32_16x16x32_bf16(a1[i][0], b0[j][0], acc[4 + i][j], 0, 0, 0);
                acc[4 + i][j] = __builtin_amdgcn_mfma_f32_16x16x32_bf16(a1[i][1], b0[j][1], acc[4 + i][j], 0, 0, 0);
            }
        __builtin_amdgcn_s_setprio(0);
        __builtin_amdgcn_s_barrier();
        asm volatile("" ::: "memory");

        // ================= phase 3 =================
#pragma unroll
        for (int j = 0; j < 2; ++j) {
            b1[j][0] = *(const short8*)(hB + (2 + j) * 1024 + aoff0);
            b1[j][1] = *(const short8*)(hB + (2 + j) * 1024 + aoff1);
        }
        if (c + 2 < NT) stageA(bb, 0, kn2);
        __builtin_amdgcn_s_barrier();
        asm volatile("s_waitcnt lgkmcnt(0)" ::: "memory");
        __builtin_amdgcn_s_setprio(1);
#pragma unroll
        for (int i = 0; i < 4; ++i)
#pragma unroll
            for (int j = 0; j < 2; ++j) {
                acc[i][2 + j] = __builtin_amdgcn_mfma_f32_16x16x32_bf16(a0[i][0], b1[j][0], acc[i][2 + j], 0, 0, 0);
                acc[i][2 + j] = __builtin_amdgcn_mfma_f32_16x16x32_bf16(a0[i][1], b1[j][1], acc[i][2 + j], 0, 0, 0);
            }
        __builtin_amdgcn_s_setprio(0);
        __builtin_amdgcn_s_barrier();
        asm volatile("" ::: "memory");

        // ================= phase 4 =================
        if (c + 2 < NT) stageA(bb, 1, kn2);
        __builtin_amdgcn_s_barrier();
        asm volatile("s_waitcnt lgkmcnt(0)" ::: "memory");
        __builtin_amdgcn_s_setprio(1);
#pragma unroll
        for (int i = 0; i < 4; ++i)
#pragma unroll
            for (int j = 0; j < 2; ++j) {
                acc[4 + i][2 + j] = __builtin_amdgcn_mfma_f32_16x16x32_bf16(a1[i][0], b1[j][0], acc[4 + i][2 + j], 0, 0, 0);
                acc[4 + i][2 + j] = __builtin_amdgcn_mfma_f32_16x16x32_bf16(a1[i][1], b1[j][1], acc[4 + i][2 + j], 0, 0, 0);
            }
        __builtin_amdgcn_s_setprio(0);
        if (c + 2 < NT) {
            asm volatile("s_waitcnt vmcnt(4)" ::: "memory");  // B(c+1) landed; A(c+2) in flight
        } else if (c + 1 < NT) {
            asm volatile("s_waitcnt vmcnt(0)" ::: "memory");  // tail drain
        }
        __builtin_amdgcn_s_barrier();
        asm volatile("" ::: "memory");
    }

    // ---- epilogue ----  C/D: row = q4*4 + r, col = ln (per 16x16 frag)
#pragma unroll
    for (int nj = 0; nj < 4; ++nj) {
        const int c0 = n0 + wn * 64 + nj * 16;  // tile-uniform column base
        const int c  = c0 + ln;

        if constexpr (MODE == 0) {
            const bool ok = (c < nmax);
#pragma unroll
            for (int mi = 0; mi < 8; ++mi) {
                const int tb = m0 + wm * 128 + mi * 16 + q4 * 4;
#pragma unroll
                for (int r = 0; r < 4; ++r) {
                    if (ok) Cb[(size_t)(tb + r) * ldc + c] = __float2bfloat16(acc[mi][nj][r]);
                }
            }
        } else {
            size_t colbase;
            if constexpr (MODE == 1) {
                const int h  = c0 / 192;
                const int e0 = c0 - h * 192;
                const int e  = e0 + ln;
                int d;
                if (e0 >= 128) {
                    const int p = e - 128;
                    d = 128 + (p & 1) * 32 + (p >> 1);
                } else {
                    d = e;
                }
                colbase = (size_t)h * OUT_HSTRIDE + d;
            } else {
                const int h  = c0 >> 8;
                const int e0 = c0 & 255;
                const int e  = e0 + ln;
                const int head = (e0 < 128) ? (32 + h) : (64 + h);
                const int d    = (e0 < 128) ? e : (e - 128);
                colbase = (size_t)head * OUT_HSTRIDE + d;
            }
#pragma unroll
            for (int mi = 0; mi < 8; ++mi) {
                const int tbase = m0 + wm * 128 + mi * 16 + q4 * 4;
#pragma unroll
                for (int r = 0; r < 4; ++r) {
                    const int t  = tbase + r;
                    const int b2 = t >> 12;
                    const int ss = t & 4095;
                    Of[(size_t)b2 * OUT_BSTRIDE + (size_t)ss * 192 + colbase] = acc[mi][nj][r];
                }
            }
        }
    }
}

// ---------------------------------------------------------------------------
// RMSNorm (in-place on bf16 ws) + k_pe deepseek-transpose broadcast (fp32 out)
// + value zero-pad (fp32 out).
// ---------------------------------------------------------------------------
__global__ __launch_bounds__(256) void norm_kpe(bf16* __restrict__ q_a,
                                                bf16* __restrict__ ckv,
                                                const float* __restrict__ qw,
                                                const float* __restrict__ kw,
                                                float* __restrict__ out) {
    __shared__ float red[4];
    __shared__ float skpe[64];
    const int tid = threadIdx.x;
    const int r   = blockIdx.x;

    if (r < 8192) {
        bf16* row = q_a + (size_t)r * 1536;
        float x[6];
#pragma unroll
        for (int k = 0; k < 6; ++k) x[k] = __bfloat162float(row[tid + k * 256]);
        float ss = 0.f;
#pragma unroll
        for (int k = 0; k < 6; ++k) ss += x[k] * x[k];
#pragma unroll
        for (int o = 32; o > 0; o >>= 1) ss += __shfl_down(ss, o, 64);
        if ((tid & 63) == 0) red[tid >> 6] = ss;
        __syncthreads();
        const float tot   = red[0] + red[1] + red[2] + red[3];
        const float scale = rsqrtf(tot * (1.0f / 1536.0f) + 1e-6f);
#pragma unroll
        for (int k = 0; k < 6; ++k) {
            const float w = qw[tid + k * 256];
            row[tid + k * 256] = __float2bfloat16(x[k] * scale * w);
        }
    } else {
        const int t = r - 8192;
        bf16* row   = ckv + (size_t)t * 576;
        float x0 = __bfloat162float(row[tid]);
        float x1 = __bfloat162float(row[tid + 256]);
        if (tid < 64) skpe[tid] = __bfloat162float(row[512 + tid]);
        float ss = x0 * x0 + x1 * x1;
#pragma unroll
        for (int o = 32; o > 0; o >>= 1) ss += __shfl_down(ss, o, 64);
        if ((tid & 63) == 0) red[tid >> 6] = ss;
        __syncthreads();
        const float tot   = red[0] + red[1] + red[2] + red[3];
        const float scale = rsqrtf(tot * (1.0f / 512.0f) + 1e-6f);
        row[tid]       = __float2bfloat16(x0 * scale * kw[tid]);
        row[tid + 256] = __float2bfloat16(x1 * scale * kw[tid + 256]);

        const int i  = tid & 63;
        const int hg = tid >> 6;
        const float v = skpe[2 * (i & 31) + (i >> 5)];
        const int bb  = t >> 12;
        const int ssx = t & 4095;
        float* obase = out + (size_t)bb * OUT_BSTRIDE + (size_t)ssx * 192 + 128 + i;
#pragma unroll
        for (int h = 0; h < 8; ++h) {
            const int head = hg * 8 + h;
            obase[(size_t)(32 + head) * OUT_HSTRIDE] = v;
            obase[(size_t)(64 + head) * OUT_HSTRIDE] = 0.0f;
        }
    }
}

extern "C" void kernel_launch(void* const* d_in, const int* in_sizes, int n_in,
                              void* d_out, int out_size, void* d_ws, size_t ws_size,
                              hipStream_t stream) {
    const float* hidden = (const float*)d_in[0];   // 8192 x 4096
    const float* q_a_w  = (const float*)d_in[1];   // 1536 x 4096
    const float* q_b_w  = (const float*)d_in[2];   // 6144 x 1536
    const float* kv_a_w = (const float*)d_in[3];   // 576  x 4096
    const float* kv_b_w = (const float*)d_in[4];   // 8192 x 512
    const float* q_ln   = (const float*)d_in[5];   // 1536
    const float* kv_ln  = (const float*)d_in[6];   // 512
    float* out = (float*)d_out;

    // ---- workspace layout (bf16), ~146 MB ----
    bf16* hid_b  = (bf16*)d_ws;
    bf16* qaw_b  = hid_b + (size_t)8192 * 4096;
    bf16* qbw_b  = qaw_b + (size_t)1536 * 4096;
    bf16* kvaw_b = qbw_b + (size_t)6144 * 1536;
    bf16* kvbw_b = kvaw_b + (size_t)576 * 4096;
    bf16* q_a    = kvbw_b + (size_t)8192 * 512;
    bf16* ckv    = q_a + (size_t)8192 * 1536;

    dim3 blk(256);
    dim3 blk8(512);
    // ---- fp32 -> bf16 converts (memory-bound) ----
    cvt_f32_bf16<<<dim3(4096), blk, 0, stream>>>(hidden, hid_b, 8192 * 4096 / 4);
    cvt_f32_bf16<<<dim3(1024), blk, 0, stream>>>(q_a_w, qaw_b, 1536 * 4096 / 4);
    cvt_f32_bf16<<<dim3(1024), blk, 0, stream>>>(q_b_w, qbw_b, 6144 * 1536 / 4);
    cvt_f32_bf16<<<dim3(512),  blk, 0, stream>>>(kv_a_w, kvaw_b, 576 * 4096 / 4);
    cvt_f32_bf16<<<dim3(512),  blk, 0, stream>>>(kv_b_w, kvbw_b, 8192 * 512 / 4);

    // K1: fused a-projections (q_a + ckv), 256^2 8-phase (NT=64)
    gemm8<0><<<dim3(32, 9),  blk8, 0, stream>>>(hid_b, qaw_b, kvaw_b, q_a, ckv, nullptr);
    // K2: rmsnorms in-place + k_pe broadcast + value pad
    norm_kpe<<<dim3(16384), blk, 0, stream>>>(q_a, ckv, q_ln, kv_ln, out);
    // K3: q projection -> out heads 0..31 (256^2 8-phase)
    gemm8<1><<<dim3(32, 24), blk8, 0, stream>>>(q_a, qbw_b, nullptr, nullptr, nullptr, out);
    // K4: kv projection -> out heads 32..95 (256^2 8-phase)
    gemm8<2><<<dim3(32, 32), blk8, 0, stream>>>(ckv, kvbw_b, nullptr, nullptr, nullptr, out);
}

// Round 3
// 1228.286 us; speedup vs baseline: 1.0627x; 1.0627x over previous
//
#include <hip/hip_runtime.h>
#include <hip/hip_bf16.h>

typedef __hip_bfloat16 bf16;
typedef __attribute__((ext_vector_type(8))) short short8;
typedef __attribute__((ext_vector_type(4))) float floatx4;

struct bf16x4 { bf16 a, b, c, d; };  // 8-byte packed store unit

// ---- problem constants ----
// B=2, S=4096, T=8192 tokens
// out shape (2, 96, 4096, 192) fp32: b-stride 75497472, head-stride 786432
#define OUT_BSTRIDE 75497472u
#define OUT_HSTRIDE 786432u

__device__ __forceinline__ void gload_lds16(const bf16* g, bf16* l) {
    __builtin_amdgcn_global_load_lds((const __attribute__((address_space(1))) void*)g,
                                     (__attribute__((address_space(3))) void*)l,
                                     16, 0, 0);
}

// ---------------------------------------------------------------------------
// Fused fp32 -> bf16 conversion of ALL five inputs in one launch.
// The five bf16 destinations are contiguous in the workspace, so dst index
// is global; only the source pointer needs a range select.
// ---------------------------------------------------------------------------
__global__ __launch_bounds__(256) void cvt_all(const float* __restrict__ s0,
                                               const float* __restrict__ s1,
                                               const float* __restrict__ s2,
                                               const float* __restrict__ s3,
                                               const float* __restrict__ s4,
                                               bf16* __restrict__ dst) {
    constexpr int N0 = 8192 * 4096 / 4;   // hidden
    constexpr int N1 = 1536 * 4096 / 4;   // q_a_w
    constexpr int N2 = 6144 * 1536 / 4;   // q_b_w
    constexpr int N3 = 576 * 4096 / 4;    // kv_a_w
    constexpr int N4 = 8192 * 512 / 4;    // kv_b_w
    constexpr int E0 = N0, E1 = E0 + N1, E2 = E1 + N2, E3 = E2 + N3, E4 = E3 + N4;
    const int stride = gridDim.x * blockDim.x;
    for (int i = blockIdx.x * blockDim.x + threadIdx.x; i < E4; i += stride) {
        const float4* sp;
        int j;
        if (i < E0)      { sp = (const float4*)s0; j = i; }
        else if (i < E1) { sp = (const float4*)s1; j = i - E0; }
        else if (i < E2) { sp = (const float4*)s2; j = i - E1; }
        else if (i < E3) { sp = (const float4*)s3; j = i - E2; }
        else             { sp = (const float4*)s4; j = i - E3; }
        const float4 v = sp[j];
        bf16x4 o;
        o.a = __float2bfloat16(v.x);
        o.b = __float2bfloat16(v.y);
        o.c = __float2bfloat16(v.z);
        o.d = __float2bfloat16(v.w);
        ((bf16x4*)dst)[i] = o;
    }
}

// ---------------------------------------------------------------------------
// 128x128 tile bf16 GEMM (m97 2-phase structure), C = A * B^T, K=4096.
// Fused a-projections: grid.y<12 -> B=q_a_w (N=1536) -> Cq bf16
//                      grid.y>=12 -> B=kv_a_w (N=576, clamp+mask) -> Ckv bf16
// ~3 blocks/CU: inter-block overlap hides staging stalls and epilogue.
// ---------------------------------------------------------------------------
__global__ __launch_bounds__(256) void gemm_bt0(const bf16* __restrict__ A,
                                                const bf16* __restrict__ Bq,
                                                const bf16* __restrict__ Bkv,
                                                bf16* __restrict__ Cq,
                                                bf16* __restrict__ Ckv) {
    constexpr int K   = 4096;
    constexpr int LDA = 4096;
    constexpr int LDB = 4096;

    __shared__ __align__(16) bf16 sA[128 * 32];
    __shared__ __align__(16) bf16 sB[128 * 32];

    const int tid = threadIdx.x;
    const int m0  = blockIdx.x * 128;

    const bf16* Bsel;
    bf16* Cbf;
    int n0, nmax, ldc;
    if (blockIdx.y < 12) {
        Bsel = Bq;  n0 = blockIdx.y * 128;        nmax = 1536; ldc = 1536; Cbf = Cq;
    } else {
        Bsel = Bkv; n0 = (blockIdx.y - 12) * 128; nmax = 576;  ldc = 576;  Cbf = Ckv;
    }

    const int r0 = tid >> 2;        // row 0..63
    const int kc = tid & 3;         // 8-elem k-chunk 0..3
    const bf16* ga0 = A + (size_t)(m0 + r0) * LDA + kc * 8;
    const bf16* ga1 = ga0 + (size_t)64 * LDA;
    int br0 = n0 + r0;      if (br0 > nmax - 1) br0 = nmax - 1;
    int br1 = n0 + r0 + 64; if (br1 > nmax - 1) br1 = nmax - 1;
    const bf16* gb0 = Bsel + (size_t)br0 * LDB + kc * 8;
    const bf16* gb1 = Bsel + (size_t)br1 * LDB + kc * 8;
    bf16* lA0 = sA + tid * 8;
    bf16* lA1 = sA + (tid + 256) * 8;
    bf16* lB0 = sB + tid * 8;
    bf16* lB1 = sB + (tid + 256) * 8;

    const int lane = tid & 63;
    const int wid  = tid >> 6;
    const int wm   = wid >> 1;
    const int wn   = wid & 1;
    const int ln   = lane & 15;
    const int qo   = (lane >> 4) * 8;

    const short8* pa[4];
    const short8* pb[4];
#pragma unroll
    for (int i = 0; i < 4; ++i) {
        pa[i] = (const short8*)(sA + (wm * 64 + i * 16 + ln) * 32 + qo);
        pb[i] = (const short8*)(sB + (wn * 64 + i * 16 + ln) * 32 + qo);
    }

    floatx4 acc[4][4];
#pragma unroll
    for (int i = 0; i < 4; ++i)
#pragma unroll
        for (int j = 0; j < 4; ++j) acc[i][j] = (floatx4){0.f, 0.f, 0.f, 0.f};

    for (int k0 = 0; k0 < K; k0 += 32) {
        gload_lds16(ga0, lA0);
        gload_lds16(ga1, lA1);
        gload_lds16(gb0, lB0);
        gload_lds16(gb1, lB1);
        ga0 += 32; ga1 += 32; gb0 += 32; gb1 += 32;
        __syncthreads();

        short8 af[4], bfr[4];
#pragma unroll
        for (int i = 0; i < 4; ++i) af[i] = *pa[i];
#pragma unroll
        for (int j = 0; j < 4; ++j) bfr[j] = *pb[j];
#pragma unroll
        for (int i = 0; i < 4; ++i)
#pragma unroll
            for (int j = 0; j < 4; ++j)
                acc[i][j] = __builtin_amdgcn_mfma_f32_16x16x32_bf16(af[i], bfr[j], acc[i][j], 0, 0, 0);
        __syncthreads();
    }

    const int rowq = (lane >> 4) * 4;
#pragma unroll
    for (int j = 0; j < 4; ++j) {
        const int c = n0 + wn * 64 + j * 16 + ln;
        const bool ok = (c < nmax);
#pragma unroll
        for (int i = 0; i < 4; ++i) {
            const int t = m0 + wm * 64 + i * 16 + rowq;
#pragma unroll
            for (int r = 0; r < 4; ++r) {
                if (ok) Cbf[(size_t)(t + r) * ldc + c] = __float2bfloat16(acc[i][j][r]);
            }
        }
    }
}

// ---------------------------------------------------------------------------
// 256x256 tile, BK=64, 8-wave (2Mx4N), 8-phase counted-vmcnt bf16 GEMM.
// C = A * B^T, fp32 scattered epilogue into out tensor.  (round-1 version,
// no XCD swizzle — measured equal to the 128^2 structure on K3/K4.)
// MODE 1: A=q_a_norm (K=1536), B=q_b_w -> q layout + pe permute (heads 0..31)
// MODE 2: A=ckv_norm (lda=576, K=512), B=kv_b_w -> k_nope/value (heads 32..95)
// ---------------------------------------------------------------------------
template <int MODE>
__global__ __launch_bounds__(512) void gemm8(const bf16* __restrict__ A,
                                             const bf16* __restrict__ B,
                                             float* __restrict__ Of) {
    constexpr int K   = (MODE == 1) ? 1536 : 512;
    constexpr int LDA = (MODE == 1) ? 1536 : 576;
    constexpr int LDB = (MODE == 1) ? 1536 : 512;
    constexpr int NT  = K / 64;

    __shared__ __align__(16) bf16 sA[2][2][128 * 64];  // [buf][half][row*64+k]
    __shared__ __align__(16) bf16 sB[2][2][128 * 64];

    const int tid = threadIdx.x;
    const int m0  = blockIdx.x * 256;
    const int n0  = blockIdx.y * 256;

    const int srow   = tid >> 3;                  // 0..63
    const int schunk = (tid & 7) ^ (srow & 7);
    const bf16* gA0 = A + (size_t)(m0 + srow) * LDA + schunk * 8;
    const bf16* gA1 = gA0 + (size_t)64 * LDA;
    const bf16* gB0 = B + (size_t)(n0 + srow) * LDB + schunk * 8;
    const bf16* gB1 = gB0 + (size_t)64 * LDB;

    auto stageA = [&](int bb, int h, int k0) {
        bf16* d = &sA[bb][h][tid * 8];
        const size_t ho = (size_t)h * (128 * LDA) + k0;
        gload_lds16(gA0 + ho, d);
        gload_lds16(gA1 + ho, d + 4096);
    };
    auto stageB = [&](int bb, int h, int k0) {
        bf16* d = &sB[bb][h][tid * 8];
        const size_t ho = (size_t)h * (128 * LDB) + k0;
        gload_lds16(gB0 + ho, d);
        gload_lds16(gB1 + ho, d + 4096);
    };

    const int lane = tid & 63;
    const int wid  = tid >> 6;        // 0..7
    const int wm   = wid >> 2;        // 0..1 -> rows wm*128..+127
    const int wn   = wid & 3;         // 0..3 -> cols wn*64..+63
    const int ln   = lane & 15;
    const int q4   = lane >> 4;       // 0..3
    const int swz  = ln & 7;          // row&7 for all this lane's frag rows
    const int aoff0 = ln * 64 + ((q4 ^ swz) * 8);        // kk=0
    const int aoff1 = ln * 64 + (((4 + q4) ^ swz) * 8);  // kk=1

    floatx4 acc[8][4];
#pragma unroll
    for (int i = 0; i < 8; ++i)
#pragma unroll
        for (int j = 0; j < 4; ++j) acc[i][j] = (floatx4){0.f, 0.f, 0.f, 0.f};

    stageA(0, 0, 0);  stageA(0, 1, 0);
    stageB(0, 0, 0);  stageB(0, 1, 0);
    stageA(1, 0, 64); stageA(1, 1, 64);
    asm volatile("s_waitcnt vmcnt(4)" ::: "memory");
    __builtin_amdgcn_s_barrier();
    asm volatile("" ::: "memory");

    short8 a0[4][2], a1[4][2], b0[2][2], b1[2][2];

    for (int c = 0; c < NT; ++c) {
        const int bb = c & 1;
        const bf16* hA = &sA[bb][wm][0];
        const bf16* hB = &sB[bb][wn >> 1][(wn & 1) * 4096];
        const int kn1 = (c + 1) * 64;
        const int kn2 = (c + 2) * 64;

        // ================= phase 1 =================
#pragma unroll
        for (int i = 0; i < 4; ++i) {
            a0[i][0] = *(const short8*)(hA + i * 1024 + aoff0);
            a0[i][1] = *(const short8*)(hA + i * 1024 + aoff1);
        }
#pragma unroll
        for (int j = 0; j < 2; ++j) {
            b0[j][0] = *(const short8*)(hB + j * 1024 + aoff0);
            b0[j][1] = *(const short8*)(hB + j * 1024 + aoff1);
        }
        if (c + 1 < NT) stageB(bb ^ 1, 0, kn1);
        __builtin_amdgcn_s_barrier();
        asm volatile("s_waitcnt lgkmcnt(0)" ::: "memory");
        __builtin_amdgcn_s_setprio(1);
#pragma unroll
        for (int i = 0; i < 4; ++i)
#pragma unroll
            for (int j = 0; j < 2; ++j) {
                acc[i][j] = __builtin_amdgcn_mfma_f32_16x16x32_bf16(a0[i][0], b0[j][0], acc[i][j], 0, 0, 0);
                acc[i][j] = __builtin_amdgcn_mfma_f32_16x16x32_bf16(a0[i][1], b0[j][1], acc[i][j], 0, 0, 0);
            }
        __builtin_amdgcn_s_setprio(0);
        __builtin_amdgcn_s_barrier();
        asm volatile("" ::: "memory");

        // ================= phase 2 =================
#pragma unroll
        for (int i = 0; i < 4; ++i) {
            a1[i][0] = *(const short8*)(hA + 4096 + i * 1024 + aoff0);
            a1[i][1] = *(const short8*)(hA + 4096 + i * 1024 + aoff1);
        }
        if (c + 1 < NT) stageB(bb ^ 1, 1, kn1);
        __builtin_amdgcn_s_barrier();
        asm volatile("s_waitcnt lgkmcnt(0)" ::: "memory");
        __builtin_amdgcn_s_setprio(1);
#pragma unroll
        for (int i = 0; i < 4; ++i)
#pragma unroll
            for (int j = 0; j < 2; ++j) {
                acc[4 + i][j] = __builtin_amdgcn_mfma_f32_16x16x32_bf16(a1[i][0], b0[j][0], acc[4 + i][j], 0, 0, 0);
                acc[4 + i][j] = __builtin_amdgcn_mfma_f32_16x16x32_bf16(a1[i][1], b0[j][1], acc[4 + i][j], 0, 0, 0);
            }
        __builtin_amdgcn_s_setprio(0);
        __builtin_amdgcn_s_barrier();
        asm volatile("" ::: "memory");

        // ================= phase 3 =================
#pragma unroll
        for (int j = 0; j < 2; ++j) {
            b1[j][0] = *(const short8*)(hB + (2 + j) * 1024 + aoff0);
            b1[j][1] = *(const short8*)(hB + (2 + j) * 1024 + aoff1);
        }
        if (c + 2 < NT) stageA(bb, 0, kn2);
        __builtin_amdgcn_s_barrier();
        asm volatile("s_waitcnt lgkmcnt(0)" ::: "memory");
        __builtin_amdgcn_s_setprio(1);
#pragma unroll
        for (int i = 0; i < 4; ++i)
#pragma unroll
            for (int j = 0; j < 2; ++j) {
                acc[i][2 + j] = __builtin_amdgcn_mfma_f32_16x16x32_bf16(a0[i][0], b1[j][0], acc[i][2 + j], 0, 0, 0);
                acc[i][2 + j] = __builtin_amdgcn_mfma_f32_16x16x32_bf16(a0[i][1], b1[j][1], acc[i][2 + j], 0, 0, 0);
            }
        __builtin_amdgcn_s_setprio(0);
        __builtin_amdgcn_s_barrier();
        asm volatile("" ::: "memory");

        // ================= phase 4 =================
        if (c + 2 < NT) stageA(bb, 1, kn2);
        __builtin_amdgcn_s_barrier();
        asm volatile("s_waitcnt lgkmcnt(0)" ::: "memory");
        __builtin_amdgcn_s_setprio(1);
#pragma unroll
        for (int i = 0; i < 4; ++i)
#pragma unroll
            for (int j = 0; j < 2; ++j) {
                acc[4 + i][2 + j] = __builtin_amdgcn_mfma_f32_16x16x32_bf16(a1[i][0], b1[j][0], acc[4 + i][2 + j], 0, 0, 0);
                acc[4 + i][2 + j] = __builtin_amdgcn_mfma_f32_16x16x32_bf16(a1[i][1], b1[j][1], acc[4 + i][2 + j], 0, 0, 0);
            }
        __builtin_amdgcn_s_setprio(0);
        if (c + 2 < NT) {
            asm volatile("s_waitcnt vmcnt(4)" ::: "memory");  // B(c+1) landed; A(c+2) in flight
        } else if (c + 1 < NT) {
            asm volatile("s_waitcnt vmcnt(0)" ::: "memory");  // tail drain
        }
        __builtin_amdgcn_s_barrier();
        asm volatile("" ::: "memory");
    }

    // ---- epilogue ----  C/D: row = q4*4 + r, col = ln (per 16x16 frag)
#pragma unroll
    for (int nj = 0; nj < 4; ++nj) {
        const int c0 = n0 + wn * 64 + nj * 16;  // tile-uniform column base
        size_t colbase;
        if constexpr (MODE == 1) {
            const int h  = c0 / 192;
            const int e0 = c0 - h * 192;
            const int e  = e0 + ln;
            int d;
            if (e0 >= 128) {
                const int p = e - 128;
                d = 128 + (p & 1) * 32 + (p >> 1);
            } else {
                d = e;
            }
            colbase = (size_t)h * OUT_HSTRIDE + d;
        } else {
            const int h  = c0 >> 8;
            const int e0 = c0 & 255;
            const int e  = e0 + ln;
            const int head = (e0 < 128) ? (32 + h) : (64 + h);
            const int d    = (e0 < 128) ? e : (e - 128);
            colbase = (size_t)head * OUT_HSTRIDE + d;
        }
#pragma unroll
        for (int mi = 0; mi < 8; ++mi) {
            const int tbase = m0 + wm * 128 + mi * 16 + q4 * 4;
#pragma unroll
            for (int r = 0; r < 4; ++r) {
                const int t  = tbase + r;
                const int b2 = t >> 12;
                const int ss = t & 4095;
                Of[(size_t)b2 * OUT_BSTRIDE + (size_t)ss * 192 + colbase] = acc[mi][nj][r];
            }
        }
    }
}

// ---------------------------------------------------------------------------
// RMSNorm (in-place on bf16 ws) + k_pe deepseek-transpose broadcast (fp32 out)
// + value zero-pad (fp32 out).
// ---------------------------------------------------------------------------
__global__ __launch_bounds__(256) void norm_kpe(bf16* __restrict__ q_a,
                                                bf16* __restrict__ ckv,
                                                const float* __restrict__ qw,
                                                const float* __restrict__ kw,
                                                float* __restrict__ out) {
    __shared__ float red[4];
    __shared__ float skpe[64];
    const int tid = threadIdx.x;
    const int r   = blockIdx.x;

    if (r < 8192) {
        bf16* row = q_a + (size_t)r * 1536;
        float x[6];
#pragma unroll
        for (int k = 0; k < 6; ++k) x[k] = __bfloat162float(row[tid + k * 256]);
        float ss = 0.f;
#pragma unroll
        for (int k = 0; k < 6; ++k) ss += x[k] * x[k];
#pragma unroll
        for (int o = 32; o > 0; o >>= 1) ss += __shfl_down(ss, o, 64);
        if ((tid & 63) == 0) red[tid >> 6] = ss;
        __syncthreads();
        const float tot   = red[0] + red[1] + red[2] + red[3];
        const float scale = rsqrtf(tot * (1.0f / 1536.0f) + 1e-6f);
#pragma unroll
        for (int k = 0; k < 6; ++k) {
            const float w = qw[tid + k * 256];
            row[tid + k * 256] = __float2bfloat16(x[k] * scale * w);
        }
    } else {
        const int t = r - 8192;
        bf16* row   = ckv + (size_t)t * 576;
        float x0 = __bfloat162float(row[tid]);
        float x1 = __bfloat162float(row[tid + 256]);
        if (tid < 64) skpe[tid] = __bfloat162float(row[512 + tid]);
        float ss = x0 * x0 + x1 * x1;
#pragma unroll
        for (int o = 32; o > 0; o >>= 1) ss += __shfl_down(ss, o, 64);
        if ((tid & 63) == 0) red[tid >> 6] = ss;
        __syncthreads();
        const float tot   = red[0] + red[1] + red[2] + red[3];
        const float scale = rsqrtf(tot * (1.0f / 512.0f) + 1e-6f);
        row[tid]       = __float2bfloat16(x0 * scale * kw[tid]);
        row[tid + 256] = __float2bfloat16(x1 * scale * kw[tid + 256]);

        const int i  = tid & 63;
        const int hg = tid >> 6;
        const float v = skpe[2 * (i & 31) + (i >> 5)];
        const int bb  = t >> 12;
        const int ssx = t & 4095;
        float* obase = out + (size_t)bb * OUT_BSTRIDE + (size_t)ssx * 192 + 128 + i;
#pragma unroll
        for (int h = 0; h < 8; ++h) {
            const int head = hg * 8 + h;
            obase[(size_t)(32 + head) * OUT_HSTRIDE] = v;
            obase[(size_t)(64 + head) * OUT_HSTRIDE] = 0.0f;
        }
    }
}

extern "C" void kernel_launch(void* const* d_in, const int* in_sizes, int n_in,
                              void* d_out, int out_size, void* d_ws, size_t ws_size,
                              hipStream_t stream) {
    const float* hidden = (const float*)d_in[0];   // 8192 x 4096
    const float* q_a_w  = (const float*)d_in[1];   // 1536 x 4096
    const float* q_b_w  = (const float*)d_in[2];   // 6144 x 1536
    const float* kv_a_w = (const float*)d_in[3];   // 576  x 4096
    const float* kv_b_w = (const float*)d_in[4];   // 8192 x 512
    const float* q_ln   = (const float*)d_in[5];   // 1536
    const float* kv_ln  = (const float*)d_in[6];   // 512
    float* out = (float*)d_out;

    // ---- workspace layout (bf16), ~146 MB ----
    bf16* hid_b  = (bf16*)d_ws;
    bf16* qaw_b  = hid_b + (size_t)8192 * 4096;
    bf16* qbw_b  = qaw_b + (size_t)1536 * 4096;
    bf16* kvaw_b = qbw_b + (size_t)6144 * 1536;
    bf16* kvbw_b = kvaw_b + (size_t)576 * 4096;
    bf16* q_a    = kvbw_b + (size_t)8192 * 512;
    bf16* ckv    = q_a + (size_t)8192 * 1536;

    dim3 blk(256);
    dim3 blk8(512);
    // K0: all five fp32 -> bf16 converts in ONE launch (dsts contiguous in ws)
    cvt_all<<<dim3(4096), blk, 0, stream>>>(hidden, q_a_w, q_b_w, kv_a_w, kv_b_w, hid_b);

    // K1: fused a-projections (q_a + ckv), 128^2 2-phase, ~3 blocks/CU
    gemm_bt0<<<dim3(64, 17), blk, 0, stream>>>(hid_b, qaw_b, kvaw_b, q_a, ckv);
    // K2: rmsnorms in-place + k_pe broadcast + value pad
    norm_kpe<<<dim3(16384), blk, 0, stream>>>(q_a, ckv, q_ln, kv_ln, out);
    // K3: q projection -> out heads 0..31 (256^2 8-phase)
    gemm8<1><<<dim3(32, 24), blk8, 0, stream>>>(q_a, qbw_b, out);
    // K4: kv projection -> out heads 32..95 (256^2 8-phase)
    gemm8<2><<<dim3(32, 32), blk8, 0, stream>>>(ckv, kvbw_b, out);
}